// Round 15
// baseline (2792.181 us; speedup 1.0000x reference)
//
#include <hip/hip_runtime.h>
#include <hip/hip_bf16.h>

typedef __attribute__((ext_vector_type(8))) short short8;
typedef __attribute__((ext_vector_type(4))) float floatx4;
typedef unsigned short u16;
typedef unsigned long long u64;

#define SCOPE_AGENT __HIP_MEMORY_SCOPE_AGENT

// B=128, T=256, D=6, H=512, 4H=2048, NC=4, PS=12

__device__ __forceinline__ u16 f2b(float f){
  union { float fl; unsigned u; } v; v.fl = f;
  unsigned r = v.u + 0x7fffu + ((v.u >> 16) & 1u);   // RNE bf16
  return (u16)(r >> 16);
}
__device__ __forceinline__ float b2f(u16 b){
  union { unsigned u; float f; } v; v.u = ((unsigned)b) << 16; return v.f;
}

// ---- device-coherent (agent) primitives ----
// agent-scope load = `sc1` on gfx950. ldc8 = 16B-wide same coherence class.
// ISSUE-ONLY: caller must s_waitcnt vmcnt(0) before consuming.
__device__ __forceinline__ short8 ldc8(const u16* p){
  short8 r;
  asm volatile("global_load_dwordx4 %0, %1, off sc1" : "=&v"(r) : "v"(p));
  return r;
}
__device__ __forceinline__ u64 ldc64(const u64* p){
  return __hip_atomic_load(p, __ATOMIC_RELAXED, SCOPE_AGENT);
}
__device__ __forceinline__ void stc64(u64* p, u64 v){
  __hip_atomic_store(p, v, __ATOMIC_RELAXED, SCOPE_AGENT);
}

// poll deadline (~0.5 s @ 100 MHz wall clock)
__device__ __forceinline__ bool expired(long long t0){
  return (wall_clock64() - t0) > 50000000LL;
}

// ---------------- prep kernels (R0 verbatim) ----------------

__global__ void reorder_w_k(const float* __restrict__ W, u16* __restrict__ out){
  int idx = blockIdx.x*256 + threadIdx.x;       // 2048*512
  int r = idx >> 9, k = idx & 511;
  int rp = ((r & 511) << 2) | (r >> 9);
  out[rp*512 + k] = f2b(W[idx]);
}
__global__ void prep_wx0_k(const float* __restrict__ W, u16* __restrict__ out){
  int idx = blockIdx.x*256 + threadIdx.x;       // 2048*32
  int r = idx >> 5, k = idx & 31;
  int rp = ((r & 511) << 2) | (r >> 9);
  out[rp*32 + k] = (k < 6) ? f2b(W[r*6 + k]) : (u16)0;
}
__global__ void prep_bias_k(const float* __restrict__ bih, const float* __restrict__ bhh,
                            float* __restrict__ out){
  int r = blockIdx.x*256 + threadIdx.x;         // 2048
  int rp = ((r & 511) << 2) | (r >> 9);
  out[rp] = bih[r] + bhh[r];
}
__global__ void prep_x_k(const float* __restrict__ x, u16* __restrict__ out){
  int idx = blockIdx.x*256 + threadIdx.x;       // 256*128*32
  int t = idx >> 12; int rem = idx & 4095; int b = rem >> 5; int k = rem & 31;
  out[idx] = (k < 6) ? f2b(x[(b*256 + t)*6 + k]) : (u16)0;
}

// ---------------- persistent LSTM kernel ----------------

struct PK {
  const u16 *Xb, *Wx0, *W0hh, *W1ih, *W1hh, *Wd0ih, *Wd0hh, *Wd1ih, *Wd1hh;
  const float *Bs;              // 4x2048 gate-interleaved biases
  u16 *h0b, *h1b;               // bf16 h rings; depth 16 (deep) or 4 (shallow=R8)
  unsigned *F;                  // [0..63]=l0 (mh*32+nt), [64..127]=l1, [128..129]=heads
  const float *fcW, *fcb, *clsW, *clsb, *regW, *regb;
  float *out;
};

#define HB 65536      // u16 elements per ring slot (128 x 512)
#define DSLOT 16      // deep ring depth (4 MB total both rings)

// flag poll — wave 0 only (callers barrier afterwards). R8-proven form.
__device__ __forceinline__ void pollF(const unsigned* F, int mh, int thr0, int thr1,
                                      int thrh, long long t0){
  const int lane = threadIdx.x & 63;
  const unsigned* ap = (lane < 32) ? (F + mh*32 + lane) : (F + 64 + mh*32 + (lane - 32));
  const int thr = (lane < 32) ? thr0 : thr1;
  for(;;){
    int v = (int)__hip_atomic_load(ap, __ATOMIC_RELAXED, SCOPE_AGENT);
    bool ok = (v >= thr);
    if (thrh > 0 && lane == 0)
      ok = ok && ((int)__hip_atomic_load(F + 128 + mh, __ATOMIC_RELAXED, SCOPE_AGENT) >= thrh);
    if (__all(ok)) return;
    if (expired(t0)) return;
    if (__any((thr - v) > 2)) __builtin_amdgcn_s_sleep(16);
    else                      __builtin_amdgcn_s_sleep(1);
  }
}

// One LSTM step tile for wg (role, mh, nt): 64 batches x 64 gates (R0-proven).
// COH1/COH2: sc1 (shallow mode, MALL-coherent reads) vs plain cached loads
// (deep mode: each h address is written ONCE per 16-step wrap, the periodic
// agent-acquire fence (every 8 steps) invalidates any stale L1/L2 copy before
// the wrap -> first toucher per XCD pulls MALL->L2, co-XCD wgs hit L2 = dedup).
template<int NK1, bool COH1, bool COH2>
__device__ __forceinline__ void lstm_step(
    const u16* __restrict__ A1, int a1rowlen, const u16* __restrict__ ldsW1, int st1,
    const u16* __restrict__ A2, const u16* __restrict__ ldsW2,
    const float* __restrict__ biasp, u16* __restrict__ hdst,
    float* creg, float (*g)[69],
    int mh, int nt, int wv, int lane)
{
  const int lrow = lane & 15, kq = lane >> 4;
  const int arow = mh*64 + wv*16 + lrow;
  short8 a1[NK1], a2[16];
  {
    const u16* p1 = A1 + arow*a1rowlen + kq*8;
    #pragma unroll
    for (int k = 0; k < NK1; ++k)
      a1[k] = COH1 ? ldc8(p1 + k*32) : *(const short8*)(p1 + k*32);
    const u16* p2 = A2 + arow*512 + kq*8;
    #pragma unroll
    for (int k = 0; k < 16; ++k)
      a2[k] = COH2 ? ldc8(p2 + k*32) : *(const short8*)(p2 + k*32);
  }
  asm volatile("s_waitcnt vmcnt(0)" ::: "memory");   // drain issue-only sc1 loads
  __builtin_amdgcn_sched_barrier(0);                  // rule #18: keep MFMAs below
  floatx4 acc[4];
  #pragma unroll
  for (int nn = 0; nn < 4; ++nn) acc[nn] = (floatx4){0.f,0.f,0.f,0.f};
  #pragma unroll
  for (int nn = 0; nn < 4; ++nn){
    const u16* wb = ldsW1 + (nn*16 + lrow)*st1 + kq*8;
    #pragma unroll
    for (int k = 0; k < NK1; ++k)
      acc[nn] = __builtin_amdgcn_mfma_f32_16x16x32_bf16(a1[k], *(const short8*)(wb + k*32), acc[nn], 0,0,0);
  }
  #pragma unroll
  for (int nn = 0; nn < 4; ++nn){
    const u16* wb = ldsW2 + (nn*16 + lrow)*520 + kq*8;
    #pragma unroll
    for (int k = 0; k < 16; ++k)
      acc[nn] = __builtin_amdgcn_mfma_f32_16x16x32_bf16(a2[k], *(const short8*)(wb + k*32), acc[nn], 0,0,0);
  }
  // C/D layout: row(m) = kq*4 + r, col(n) = lane&15 -> g rows wv*16..+15 only
  #pragma unroll
  for (int nn = 0; nn < 4; ++nn){
    float bn = biasp[nn*16 + lrow];
    #pragma unroll
    for (int r = 0; r < 4; ++r)
      g[wv*16 + kq*4 + r][nn*16 + lrow] = acc[nn][r] + bn;
  }
  __builtin_amdgcn_wave_barrier();   // intra-wave LDS transpose; DS ops in-order per wave
  const int bl = lane >> 2, jq = lane & 3;
  const float* gr = g[wv*16 + bl];
  union { u16 h[4]; u64 q; } pk;
  #pragma unroll
  for (int jj = 0; jj < 4; ++jj){
    int cb = (jq*4 + jj)*4;
    float gi = gr[cb+0], gf = gr[cb+1], gg = gr[cb+2], go = gr[cb+3];
    float iv = 1.f/(1.f + expf(-gi));
    float fv = 1.f/(1.f + expf(-gf));
    float ov = 1.f/(1.f + expf(-go));
    float cn = fv*creg[jj] + iv*tanhf(gg);
    creg[jj] = cn;
    pk.h[jj] = f2b(ov * tanhf(cn));
  }
  // publish: sc1 -> MALL (drained before flag in setflag)
  stc64((u64*)(hdst + (mh*64 + wv*16 + bl)*512 + nt*16 + jq*4), pk.q);
}

// Flag protocol — IDENTICAL to R8 (flag = tau+1 after step tau):
//  enc l0 t: f0>=t, f1>=t-3 | enc l1 u: f0>=u+1, f1>=u
//  dec l0 s: f0>=256+s, f1>=256+s | dec l1 s: f0>=257+s, f1>=256+s, fh>=s-2
//  heads: cls f1>=256 | forecast s: f1>=257+s
// Ring slot for h(tau): (tau+16) & (D-1); D=16 deep / 4 shallow (R8 exact).
// Deep staleness proof: address cached <=4 steps after publish, rewritten at
// +16, re-read at +16/+17 -> hazard windows span >=12 steps; fences every 8
// steps (acquire/agent, invalidates L1+XCD L2) always land inside the window.

template<bool DEEP>
__global__ __launch_bounds__(256, 1) __attribute__((amdgpu_waves_per_eu(1, 1)))
void persist_k(PK p){
  const int w = blockIdx.x, tid = threadIdx.x;
  const int wv = tid >> 6, lane = tid & 63;
  const long long t0 = wall_clock64();
  __shared__ float g[64][69];
  extern __shared__ u16 dynW[];
  unsigned* F = p.F;
  constexpr bool HC = !DEEP;   // h loads coherent (sc1) only in shallow mode

  auto hslot = [](int tt)->size_t {
    return (size_t)((tt + 16) & (DEEP ? (DSLOT-1) : 3));
  };
  auto fence8 = [&](int tau){
    if (DEEP && (tau & 7) == 0)
      __builtin_amdgcn_fence(__ATOMIC_ACQUIRE, "agent");  // inv stale L1/L2
  };

  auto setflag = [&](int idx, unsigned val){
    __syncthreads();   // release: drains vmcnt (h stores) on every wave
    if (tid == 0) __hip_atomic_store(F + idx, val, __ATOMIC_RELAXED, SCOPE_AGENT);
  };

  if (w < 128){
    const int role = w >> 6;            // 0 = layer0 chain, 1 = layer1 chain
    const int q = w & 63;
    const int mh = q >> 5, nt = q & 31;
    const int fidx = role*64 + mh*32 + nt;
    u16* WA = dynW;
    u16* WB = dynW + 64*520;
    float creg[4] = {0.f,0.f,0.f,0.f};

    if (role == 0){
      { // preload: Wx0 slice (stride 40) + W0hh slice (stride 520)
        const unsigned* sA = (const unsigned*)(p.Wx0 + nt*64*32);
        unsigned* dA = (unsigned*)WA;
        for (int i = tid; i < 64*16; i += 256){ int r = i>>4, c = i&15; dA[r*20+c] = sA[r*16+c]; }
        const unsigned* sB = (const unsigned*)(p.W0hh + (size_t)nt*64*512);
        unsigned* dB = (unsigned*)WB;
        for (int i = tid; i < 64*256; i += 256){ int r = i>>8, c = i&255; dB[r*260+c] = sB[r*256+c]; }
      }
      const float* biasp = p.Bs + nt*64;
      __syncthreads();
      for (int t = 0; t < 256; ++t){
        if (wv == 0) pollF(F, mh, t, t-3, 0, t0);
        __syncthreads();
        fence8(t);
        lstm_step<1,false,HC>(p.Xb + t*4096, 32, WA, 40,
                              p.h0b + hslot(t-1)*HB, WB,
                              biasp, p.h0b + hslot(t)*HB, creg, g, mh, nt, wv, lane);
        setflag(fidx, t+1);
      }
      { // reload decoder l0 weights (cell state stays in regs)
        const unsigned* sA = (const unsigned*)(p.Wd0ih + (size_t)nt*64*512);
        const unsigned* sB = (const unsigned*)(p.Wd0hh + (size_t)nt*64*512);
        unsigned* dA = (unsigned*)WA; unsigned* dB = (unsigned*)WB;
        for (int i = tid; i < 64*256; i += 256){
          int r = i>>8, c = i&255;
          dA[r*260+c] = sA[r*256+c]; dB[r*260+c] = sB[r*256+c];
        }
      }
      biasp = p.Bs + 4096 + nt*64;
      __syncthreads();
      for (int s = 0; s < 12; ++s){
        if (wv == 0) pollF(F, mh, 256+s, 256+s, 0, t0);
        __syncthreads();
        fence8(256+s);
        lstm_step<16,HC,HC>(p.h1b + hslot(255+s)*HB, 512, WA, 520,
                            p.h0b + hslot(255+s)*HB, WB,
                            biasp, p.h0b + hslot(256+s)*HB, creg, g, mh, nt, wv, lane);
        setflag(fidx, 257+s);
      }
    } else {
      { // preload: W1ih + W1hh slices
        const unsigned* sA = (const unsigned*)(p.W1ih + (size_t)nt*64*512);
        const unsigned* sB = (const unsigned*)(p.W1hh + (size_t)nt*64*512);
        unsigned* dA = (unsigned*)WA; unsigned* dB = (unsigned*)WB;
        for (int i = tid; i < 64*256; i += 256){
          int r = i>>8, c = i&255;
          dA[r*260+c] = sA[r*256+c]; dB[r*260+c] = sB[r*256+c];
        }
      }
      const float* biasp = p.Bs + 2048 + nt*64;
      __syncthreads();
      for (int u = 0; u < 256; ++u){
        if (wv == 0) pollF(F, mh, u+1, u, 0, t0);
        __syncthreads();
        fence8(u);
        lstm_step<16,HC,HC>(p.h0b + hslot(u)*HB, 512, WA, 520,
                            p.h1b + hslot(u-1)*HB, WB,
                            biasp, p.h1b + hslot(u)*HB, creg, g, mh, nt, wv, lane);
        setflag(fidx, u+1);
      }
      { // reload decoder l1 weights
        const unsigned* sA = (const unsigned*)(p.Wd1ih + (size_t)nt*64*512);
        const unsigned* sB = (const unsigned*)(p.Wd1hh + (size_t)nt*64*512);
        unsigned* dA = (unsigned*)WA; unsigned* dB = (unsigned*)WB;
        for (int i = tid; i < 64*256; i += 256){
          int r = i>>8, c = i&255;
          dA[r*260+c] = sA[r*256+c]; dB[r*260+c] = sB[r*256+c];
        }
      }
      biasp = p.Bs + 6144 + nt*64;
      __syncthreads();
      for (int s = 0; s < 12; ++s){
        if (wv == 0) pollF(F, mh, 257+s, 256+s, s-2, t0);   // heads WAR: fh>=s-2
        __syncthreads();
        fence8(256+s);
        lstm_step<16,HC,HC>(p.h0b + hslot(256+s)*HB, 512, WA, 520,
                            p.h1b + hslot(255+s)*HB, WB,
                            biasp, p.h1b + hslot(256+s)*HB, creg, g, mh, nt, wv, lane);
        setflag(fidx, 257+s);
      }
    }
  } else if (w < 130){
    // ---- heads wg (one per mh half) — sc1 read path (read-once, fence-free) ----
    const int mh = w & 1;
    const int b = tid & 63, part = tid >> 6;
    const int gb = mh*64 + b;
    { // cls + reg from h1(255)
      if (wv == 0) pollF(F, mh, 0, 256, 0, t0);
      __syncthreads();
      const u64* hp = (const u64*)(p.h1b + hslot(255)*HB + gb*512 + part*128);
      float a[5] = {0.f,0.f,0.f,0.f,0.f};
      for (int c = 0; c < 32; ++c){
        u64 v = ldc64(hp + c);
        #pragma unroll
        for (int e = 0; e < 4; ++e){
          float hv = b2f((u16)(v >> (16*e)));
          int k = part*128 + c*4 + e;
          a[0] += hv * p.clsW[k];
          a[1] += hv * p.clsW[512 + k];
          a[2] += hv * p.clsW[1024 + k];
          a[3] += hv * p.clsW[1536 + k];
          a[4] += hv * p.regW[k];
        }
      }
      #pragma unroll
      for (int d = 0; d < 5; ++d) g[b][part*8 + d] = a[d];
      __syncthreads();
      if (tid < 64){
        #pragma unroll
        for (int d = 0; d < 5; ++d){
          float v = g[tid][d] + g[tid][8+d] + g[tid][16+d] + g[tid][24+d];
          if (d < 4) p.out[9216 + (mh*64 + tid)*4 + d] = v + p.clsb[d];
          else       p.out[9728 + mh*64 + tid]         = v + p.regb[0];
        }
      }
      __syncthreads();
      if (tid == 0) __hip_atomic_store(F + 128 + mh, 1u, __ATOMIC_RELAXED, SCOPE_AGENT);
    }
    for (int s = 0; s < 12; ++s){
      if (wv == 0) pollF(F, mh, 0, 257 + s, 0, t0);
      __syncthreads();
      const u64* hp = (const u64*)(p.h1b + hslot(256+s)*HB + gb*512 + part*128);
      float a[6] = {0.f,0.f,0.f,0.f,0.f,0.f};
      for (int c = 0; c < 32; ++c){
        u64 v = ldc64(hp + c);
        #pragma unroll
        for (int e = 0; e < 4; ++e){
          float hv = b2f((u16)(v >> (16*e)));
          int k = part*128 + c*4 + e;
          #pragma unroll
          for (int d = 0; d < 6; ++d) a[d] += hv * p.fcW[d*512 + k];
        }
      }
      #pragma unroll
      for (int d = 0; d < 6; ++d) g[b][part*8 + d] = a[d];
      __syncthreads();
      if (tid < 64){
        #pragma unroll
        for (int d = 0; d < 6; ++d){
          float v = g[tid][d] + g[tid][8+d] + g[tid][16+d] + g[tid][24+d];
          p.out[(mh*64 + tid)*72 + s*6 + d] = v + p.fcb[d];
        }
      }
      __syncthreads();
      if (tid == 0)
        __hip_atomic_store(F + 128 + mh, (unsigned)(s+2), __ATOMIC_RELAXED, SCOPE_AGENT);
    }
  }
}

// ---------------- launcher ----------------

extern "C" void kernel_launch(void* const* d_in, const int* in_sizes, int n_in,
                              void* d_out, int out_size, void* d_ws, size_t ws_size,
                              hipStream_t stream){
  const float* x     = (const float*)d_in[0];
  const float* eWih0 = (const float*)d_in[1];
  const float* eWhh0 = (const float*)d_in[2];
  const float* ebih0 = (const float*)d_in[3];
  const float* ebhh0 = (const float*)d_in[4];
  const float* eWih1 = (const float*)d_in[5];
  const float* eWhh1 = (const float*)d_in[6];
  const float* ebih1 = (const float*)d_in[7];
  const float* ebhh1 = (const float*)d_in[8];
  const float* dWih0 = (const float*)d_in[9];
  const float* dWhh0 = (const float*)d_in[10];
  const float* dbih0 = (const float*)d_in[11];
  const float* dbhh0 = (const float*)d_in[12];
  const float* dWih1 = (const float*)d_in[13];
  const float* dWhh1 = (const float*)d_in[14];
  const float* dbih1 = (const float*)d_in[15];
  const float* dbhh1 = (const float*)d_in[16];
  const float* fcW   = (const float*)d_in[17];
  const float* fcb   = (const float*)d_in[18];
  const float* clsW  = (const float*)d_in[19];
  const float* clsb  = (const float*)d_in[20];
  const float* regW  = (const float*)d_in[21];
  const float* regb  = (const float*)d_in[22];
  float* out = (float*)d_out;

  uintptr_t base = (uintptr_t)d_ws;
  auto carve = [&](size_t n)->void*{
    void* p = (void*)base; base += (n + 255) & ~(size_t)255; return p;
  };
  u16* Wx0b  = (u16*)carve(2048*32*2);
  u16* We0hh = (u16*)carve(2048*512*2);
  u16* We1ih = (u16*)carve(2048*512*2);
  u16* We1hh = (u16*)carve(2048*512*2);
  u16* Wd0ih = (u16*)carve(2048*512*2);
  u16* Wd0hh = (u16*)carve(2048*512*2);
  u16* Wd1ih = (u16*)carve(2048*512*2);
  u16* Wd1hh = (u16*)carve(2048*512*2);
  float* Bs  = (float*)carve(4*2048*4);
  u16* Xb    = (u16*)carve(256*128*32*2);

  // deep (depth-16) rings need only +4 MB; gate on workspace, else exact R8
  const size_t slotB   = (size_t)HB*2;                 // 131072 B per slot
  const size_t usedFix = (size_t)(base - (uintptr_t)d_ws);
  const size_t needDeep = usedFix + 2*((size_t)DSLOT*slotB + 256) + 4096;
  const bool deep = (ws_size >= needDeep);
  const size_t nslot = deep ? (size_t)DSLOT : 4;

  u16* h0b   = (u16*)carve(nslot*slotB);
  u16* h1b   = (u16*)carve(nslot*slotB);
  unsigned* F = (unsigned*)carve(192*4);

  // zero all ring slots + flags (contiguous carves; <=4.2 MB)
  (void)hipMemsetAsync(h0b, 0, 2*nslot*slotB + 768, stream);

  reorder_w_k<<<4096,256,0,stream>>>(eWhh0, We0hh);
  reorder_w_k<<<4096,256,0,stream>>>(eWih1, We1ih);
  reorder_w_k<<<4096,256,0,stream>>>(eWhh1, We1hh);
  reorder_w_k<<<4096,256,0,stream>>>(dWih0, Wd0ih);
  reorder_w_k<<<4096,256,0,stream>>>(dWhh0, Wd0hh);
  reorder_w_k<<<4096,256,0,stream>>>(dWih1, Wd1ih);
  reorder_w_k<<<4096,256,0,stream>>>(dWhh1, Wd1hh);
  prep_wx0_k<<<256,256,0,stream>>>(eWih0, Wx0b);
  prep_bias_k<<<8,256,0,stream>>>(ebih0, ebhh0, Bs);
  prep_bias_k<<<8,256,0,stream>>>(ebih1, ebhh1, Bs + 2048);
  prep_bias_k<<<8,256,0,stream>>>(dbih0, dbhh0, Bs + 4096);
  prep_bias_k<<<8,256,0,stream>>>(dbih1, dbhh1, Bs + 6144);
  prep_x_k<<<4096,256,0,stream>>>(x, Xb);

  PK p;
  p.Xb = Xb; p.Wx0 = Wx0b; p.W0hh = We0hh; p.W1ih = We1ih; p.W1hh = We1hh;
  p.Wd0ih = Wd0ih; p.Wd0hh = Wd0hh; p.Wd1ih = Wd1ih; p.Wd1hh = Wd1hh;
  p.Bs = Bs; p.h0b = h0b; p.h1b = h1b; p.F = F;
  p.fcW = fcW; p.fcb = fcb; p.clsW = clsW; p.clsb = clsb;
  p.regW = regW; p.regb = regb; p.out = out;

  const int dynLds = 2*64*520*2;   // 133,120 B (two 64x520 u16 weight slices)
  const void* kfun = deep ? (const void*)persist_k<true> : (const void*)persist_k<false>;
  (void)hipFuncSetAttribute(kfun, hipFuncAttributeMaxDynamicSharedMemorySize, dynLds);

  void* args[] = { &p };
  hipError_t e = hipLaunchCooperativeKernel(kfun, dim3(130), dim3(256),
                                            args, dynLds, stream);
  if (e != hipSuccess){
    // fallback: plain launch (130 wgs at 1 wg/CU are trivially co-resident;
    // poll deadline guards the pathological case)
    if (deep) persist_k<true><<<dim3(130), dim3(256), dynLds, stream>>>(p);
    else      persist_k<false><<<dim3(130), dim3(256), dynLds, stream>>>(p);
  }
  (void)in_sizes; (void)n_in; (void)out_size; (void)ws_size;
}

// Round 16
// 2487.121 us; speedup vs baseline: 1.1227x; 1.1227x over previous
//
#include <hip/hip_runtime.h>
#include <hip/hip_bf16.h>

typedef __attribute__((ext_vector_type(8))) short short8;
typedef __attribute__((ext_vector_type(4))) float floatx4;
typedef unsigned short u16;
typedef unsigned long long u64;

#define SCOPE_AGENT __HIP_MEMORY_SCOPE_AGENT

// B=128, T=256, D=6, H=512, 4H=2048, NC=4, PS=12

__device__ __forceinline__ u16 f2b(float f){
  union { float fl; unsigned u; } v; v.fl = f;
  unsigned r = v.u + 0x7fffu + ((v.u >> 16) & 1u);   // RNE bf16
  return (u16)(r >> 16);
}
__device__ __forceinline__ float b2f(u16 b){
  union { unsigned u; float f; } v; v.u = ((unsigned)b) << 16; return v.f;
}

// ---- device-coherent (agent) primitives ----
// agent-scope load = `sc1` on gfx950; 16B wide (coherence, not atomicity).
// ISSUE-ONLY: caller must s_waitcnt vmcnt(0) before consuming.
__device__ __forceinline__ short8 ldc8(const u16* p){
  short8 r;
  asm volatile("global_load_dwordx4 %0, %1, off sc1" : "=&v"(r) : "v"(p));
  return r;
}
__device__ __forceinline__ void stc64(u64* p, u64 v){
  __hip_atomic_store(p, v, __ATOMIC_RELAXED, SCOPE_AGENT);
}

// poll deadline (~0.5 s @ 100 MHz wall clock)
__device__ __forceinline__ bool expired(long long t0){
  return (wall_clock64() - t0) > 50000000LL;
}

// ---------------- prep kernels ----------------

__global__ void reorder_w_k(const float* __restrict__ W, u16* __restrict__ out){
  int idx = blockIdx.x*256 + threadIdx.x;       // 2048*512
  int r = idx >> 9, k = idx & 511;
  int rp = ((r & 511) << 2) | (r >> 9);
  out[rp*512 + k] = f2b(W[idx]);
}
__global__ void prep_wx0_k(const float* __restrict__ W, u16* __restrict__ out){
  int idx = blockIdx.x*256 + threadIdx.x;       // 2048*32
  int r = idx >> 5, k = idx & 31;
  int rp = ((r & 511) << 2) | (r >> 9);
  out[rp*32 + k] = (k < 6) ? f2b(W[r*6 + k]) : (u16)0;
}
__global__ void prep_bias_k(const float* __restrict__ bih, const float* __restrict__ bhh,
                            float* __restrict__ out){
  int r = blockIdx.x*256 + threadIdx.x;         // 2048
  int rp = ((r & 511) << 2) | (r >> 9);
  out[rp] = bih[r] + bhh[r];
}
__global__ void prep_x_k(const float* __restrict__ x, u16* __restrict__ out){
  int idx = blockIdx.x*256 + threadIdx.x;       // 256*128*32
  int t = idx >> 12; int rem = idx & 4095; int b = rem >> 5; int k = rem & 31;
  out[idx] = (k < 6) ? f2b(x[(b*256 + t)*6 + k]) : (u16)0;
}
// pre-fill output with biases; worker wgs atomicAdd head partials on top.
__global__ void init_out_k(float* __restrict__ out, const float* __restrict__ fcb,
                           const float* __restrict__ clsb, const float* __restrict__ regb){
  int i = blockIdx.x*256 + threadIdx.x;         // 9856 total
  if (i < 9216)       out[i] = fcb[i % 6];                 // forecast [128][12][6]
  else if (i < 9728)  out[i] = clsb[(i - 9216) & 3];       // cls [128][4]
  else if (i < 9856)  out[i] = regb[0];                    // reg [128]
}

// ---------------- persistent LSTM kernel ----------------

struct PK {
  const u16 *Xb, *Wx0, *W0hh, *W1ih, *W1hh, *Wd0ih, *Wd0hh, *Wd1ih, *Wd1hh;
  const float *Bs;              // 4x2048 gate-interleaved biases
  u16 *h0b, *h1b;               // bf16 depth-4 h rings [4][128][512], slot = tau&3
  unsigned *F;                  // [0..127]=l0 pools (bg*32+nt), [128..255]=l1
  const float *fcW, *clsW, *regW;
  float *out;
};

#define HB 65536   // u16 elements per ring slot (128 x 512)

// flag poll — wave 0 only (callers barrier afterwards). R8-proven sleep form.
// lanes 0..31: l0(bg) flags vs thr0 ; lanes 32..63: l1(bg) flags vs thr1.
__device__ __forceinline__ void pollF(const unsigned* F, int bg, int thr0, int thr1,
                                      long long t0){
  const int lane = threadIdx.x & 63;
  const unsigned* ap = (lane < 32) ? (F + bg*32 + lane)
                                   : (F + 128 + bg*32 + (lane - 32));
  const int thr = (lane < 32) ? thr0 : thr1;
  for(;;){
    int v = (int)__hip_atomic_load(ap, __ATOMIC_RELAXED, SCOPE_AGENT);
    if (__all(v >= thr)) return;
    if (expired(t0)) return;
    if (__any((thr - v) > 2)) __builtin_amdgcn_s_sleep(16);
    else                      __builtin_amdgcn_s_sleep(1);
  }
}

// One LSTM step tile for wg (role, bg, nt): 32 batches x 64 gates, 2 waves.
// Wave wv covers batches bg*32+wv*16..+16. R8-proven core (mh->bg remap).
// hout[] exports the 4 rounded h values (for inline head partials).
template<int NK1, bool COH1>
__device__ __forceinline__ void lstm_step(
    const u16* __restrict__ A1, int a1rowlen, const u16* __restrict__ ldsW1, int st1,
    const u16* __restrict__ A2, const u16* __restrict__ ldsW2,
    const float* __restrict__ biasp, u16* __restrict__ hdst,
    float* creg, float (*g)[69], float* hout,
    int bg, int nt, int wv, int lane)
{
  const int lrow = lane & 15, kq = lane >> 4;
  const int arow = bg*32 + wv*16 + lrow;
  short8 a1[NK1], a2[16];
  {
    const u16* p1 = A1 + arow*a1rowlen + kq*8;
    #pragma unroll
    for (int k = 0; k < NK1; ++k)
      a1[k] = COH1 ? ldc8(p1 + k*32) : *(const short8*)(p1 + k*32);
    const u16* p2 = A2 + arow*512 + kq*8;
    #pragma unroll
    for (int k = 0; k < 16; ++k) a2[k] = ldc8(p2 + k*32);
  }
  asm volatile("s_waitcnt vmcnt(0)" ::: "memory");   // drain issue-only sc1 loads
  __builtin_amdgcn_sched_barrier(0);                  // rule #18: keep MFMAs below
  floatx4 acc[4];
  #pragma unroll
  for (int nn = 0; nn < 4; ++nn) acc[nn] = (floatx4){0.f,0.f,0.f,0.f};
  #pragma unroll
  for (int nn = 0; nn < 4; ++nn){
    const u16* wb = ldsW1 + (nn*16 + lrow)*st1 + kq*8;
    #pragma unroll
    for (int k = 0; k < NK1; ++k)
      acc[nn] = __builtin_amdgcn_mfma_f32_16x16x32_bf16(a1[k], *(const short8*)(wb + k*32), acc[nn], 0,0,0);
  }
  #pragma unroll
  for (int nn = 0; nn < 4; ++nn){
    const u16* wb = ldsW2 + (nn*16 + lrow)*520 + kq*8;
    #pragma unroll
    for (int k = 0; k < 16; ++k)
      acc[nn] = __builtin_amdgcn_mfma_f32_16x16x32_bf16(a2[k], *(const short8*)(wb + k*32), acc[nn], 0,0,0);
  }
  // C/D layout: row(m) = kq*4 + r, col(n) = lane&15 -> g rows wv*16..+15 only
  #pragma unroll
  for (int nn = 0; nn < 4; ++nn){
    float bn = biasp[nn*16 + lrow];
    #pragma unroll
    for (int r = 0; r < 4; ++r)
      g[wv*16 + kq*4 + r][nn*16 + lrow] = acc[nn][r] + bn;
  }
  __builtin_amdgcn_wave_barrier();   // intra-wave LDS transpose
  const int bl = lane >> 2, jq = lane & 3;
  const float* gr = g[wv*16 + bl];
  union { u16 h[4]; u64 q; } pk;
  #pragma unroll
  for (int jj = 0; jj < 4; ++jj){
    int cb = (jq*4 + jj)*4;
    float gi = gr[cb+0], gf = gr[cb+1], gg = gr[cb+2], go = gr[cb+3];
    float iv = 1.f/(1.f + expf(-gi));
    float fv = 1.f/(1.f + expf(-gf));
    float ov = 1.f/(1.f + expf(-go));
    float cn = fv*creg[jj] + iv*tanhf(gg);
    creg[jj] = cn;
    pk.h[jj] = f2b(ov * tanhf(cn));
    hout[jj] = b2f(pk.h[jj]);
  }
  stc64((u64*)(hdst + (bg*32 + wv*16 + bl)*512 + nt*16 + jq*4), pk.q);
}

// Flag protocol — R8 thresholds, per-(bg) chain (8 independent chains):
//  enc l0 t: f0>=t, f1>=t-3 | enc l1 u: f0>=u+1, f1>=u
//  dec l0 s: f0>=256+s, f1>=256+s | dec l1 s: f0>=257+s, f1>=256+s
// Heads are inline in l1 wgs (atomicAdd partials) -> no heads wgs, no fh edge.
// Ring slot for h(tau): tau&3 (depth 4), dec slot = s&3.

__global__ __launch_bounds__(128, 1) __attribute__((amdgpu_waves_per_eu(1, 1)))
void persist_k(PK p){
  const int w = blockIdx.x, tid = threadIdx.x;
  const int wv = tid >> 6, lane = tid & 63;
  const long long t0 = wall_clock64();
  __shared__ float g[32][69];
  extern __shared__ u16 dynW[];
  unsigned* F = p.F;

  const int role = w >> 7;              // 0 = layer0, 1 = layer1
  const int bg   = (w >> 5) & 3;        // batch group (32 batches)
  const int nt   = w & 31;              // gate slice (64 gates)
  const int fidx = role*128 + bg*32 + nt;
  u16* WA = dynW;
  u16* WB = dynW + 64*520;
  float creg[4] = {0.f,0.f,0.f,0.f};
  float hout[4];

  auto setflag = [&](unsigned val){
    __syncthreads();   // release: drains vmcnt (h stores) on every wave
    if (tid == 0) __hip_atomic_store(F + fidx, val, __ATOMIC_RELAXED, SCOPE_AGENT);
  };

  if (role == 0){
    { // preload: Wx0 slice (stride 40) + W0hh slice (stride 520)
      const unsigned* sA = (const unsigned*)(p.Wx0 + nt*64*32);
      unsigned* dA = (unsigned*)WA;
      for (int i = tid; i < 64*16; i += 128){ int r = i>>4, c = i&15; dA[r*20+c] = sA[r*16+c]; }
      const unsigned* sB = (const unsigned*)(p.W0hh + (size_t)nt*64*512);
      unsigned* dB = (unsigned*)WB;
      for (int i = tid; i < 64*256; i += 128){ int r = i>>8, c = i&255; dB[r*260+c] = sB[r*256+c]; }
    }
    const float* biasp = p.Bs + nt*64;
    __syncthreads();
    for (int t = 0; t < 256; ++t){
      if (wv == 0) pollF(F, bg, t, t-3, t0);
      __syncthreads();
      lstm_step<1,false>(p.Xb + t*4096, 32, WA, 40,
                         p.h0b + ((t+3)&3)*HB, WB,
                         biasp, p.h0b + (t&3)*HB, creg, g, hout, bg, nt, wv, lane);
      setflag(t+1);
    }
    { // reload decoder l0 weights (cell state stays in regs)
      const unsigned* sA = (const unsigned*)(p.Wd0ih + (size_t)nt*64*512);
      const unsigned* sB = (const unsigned*)(p.Wd0hh + (size_t)nt*64*512);
      unsigned* dA = (unsigned*)WA; unsigned* dB = (unsigned*)WB;
      for (int i = tid; i < 64*256; i += 128){
        int r = i>>8, c = i&255;
        dA[r*260+c] = sA[r*256+c]; dB[r*260+c] = sB[r*256+c];
      }
    }
    biasp = p.Bs + 4096 + nt*64;
    __syncthreads();
    for (int s = 0; s < 12; ++s){
      if (wv == 0) pollF(F, bg, 256+s, 256+s, t0);
      __syncthreads();
      lstm_step<16,true>(p.h1b + ((s+3)&3)*HB, 512, WA, 520,
                         p.h0b + ((s+3)&3)*HB, WB,
                         biasp, p.h0b + (s&3)*HB, creg, g, hout, bg, nt, wv, lane);
      setflag(257+s);
    }
  } else {
    { // preload: W1ih + W1hh slices
      const unsigned* sA = (const unsigned*)(p.W1ih + (size_t)nt*64*512);
      const unsigned* sB = (const unsigned*)(p.W1hh + (size_t)nt*64*512);
      unsigned* dA = (unsigned*)WA; unsigned* dB = (unsigned*)WB;
      for (int i = tid; i < 64*256; i += 128){
        int r = i>>8, c = i&255;
        dA[r*260+c] = sA[r*256+c]; dB[r*260+c] = sB[r*256+c];
      }
    }
    const float* biasp = p.Bs + 2048 + nt*64;
    __syncthreads();
    const int batch = bg*32 + wv*16 + (lane >> 2);
    const int jq = lane & 3;
    for (int u = 0; u < 256; ++u){
      if (wv == 0) pollF(F, bg, u+1, u, t0);
      __syncthreads();
      lstm_step<16,true>(p.h0b + (u&3)*HB, 512, WA, 520,
                         p.h1b + ((u+3)&3)*HB, WB,
                         biasp, p.h1b + (u&3)*HB, creg, g, hout, bg, nt, wv, lane);
      if (u == 255){
        // cls + reg partials from h1(255) block held in hout
        float a[5] = {0.f,0.f,0.f,0.f,0.f};
        #pragma unroll
        for (int jj = 0; jj < 4; ++jj){
          int col = nt*16 + jq*4 + jj;
          float hv = hout[jj];
          a[0] += hv * p.clsW[col];
          a[1] += hv * p.clsW[512 + col];
          a[2] += hv * p.clsW[1024 + col];
          a[3] += hv * p.clsW[1536 + col];
          a[4] += hv * p.regW[col];
        }
        #pragma unroll
        for (int c = 0; c < 4; ++c) atomicAdd(&p.out[9216 + batch*4 + c], a[c]);
        atomicAdd(&p.out[9728 + batch], a[4]);
      }
      setflag(u+1);
    }
    { // reload decoder l1 weights
      const unsigned* sA = (const unsigned*)(p.Wd1ih + (size_t)nt*64*512);
      const unsigned* sB = (const unsigned*)(p.Wd1hh + (size_t)nt*64*512);
      unsigned* dA = (unsigned*)WA; unsigned* dB = (unsigned*)WB;
      for (int i = tid; i < 64*256; i += 128){
        int r = i>>8, c = i&255;
        dA[r*260+c] = sA[r*256+c]; dB[r*260+c] = sB[r*256+c];
      }
    }
    biasp = p.Bs + 6144 + nt*64;
    __syncthreads();
    for (int s = 0; s < 12; ++s){
      if (wv == 0) pollF(F, bg, 257+s, 256+s, t0);
      __syncthreads();
      lstm_step<16,true>(p.h0b + (s&3)*HB, 512, WA, 520,
                         p.h1b + ((s+3)&3)*HB, WB,
                         biasp, p.h1b + (s&3)*HB, creg, g, hout, bg, nt, wv, lane);
      // forecast partials: out[batch][s][d] += sum_cols h1*fcW
      #pragma unroll
      for (int d = 0; d < 6; ++d){
        float ad = 0.f;
        #pragma unroll
        for (int jj = 0; jj < 4; ++jj)
          ad += hout[jj] * p.fcW[d*512 + nt*16 + jq*4 + jj];
        atomicAdd(&p.out[batch*72 + s*6 + d], ad);
      }
      setflag(257+s);
    }
  }
}

// ---------------- launcher ----------------

extern "C" void kernel_launch(void* const* d_in, const int* in_sizes, int n_in,
                              void* d_out, int out_size, void* d_ws, size_t ws_size,
                              hipStream_t stream){
  const float* x     = (const float*)d_in[0];
  const float* eWih0 = (const float*)d_in[1];
  const float* eWhh0 = (const float*)d_in[2];
  const float* ebih0 = (const float*)d_in[3];
  const float* ebhh0 = (const float*)d_in[4];
  const float* eWih1 = (const float*)d_in[5];
  const float* eWhh1 = (const float*)d_in[6];
  const float* ebih1 = (const float*)d_in[7];
  const float* ebhh1 = (const float*)d_in[8];
  const float* dWih0 = (const float*)d_in[9];
  const float* dWhh0 = (const float*)d_in[10];
  const float* dbih0 = (const float*)d_in[11];
  const float* dbhh0 = (const float*)d_in[12];
  const float* dWih1 = (const float*)d_in[13];
  const float* dWhh1 = (const float*)d_in[14];
  const float* dbih1 = (const float*)d_in[15];
  const float* dbhh1 = (const float*)d_in[16];
  const float* fcW   = (const float*)d_in[17];
  const float* fcb   = (const float*)d_in[18];
  const float* clsW  = (const float*)d_in[19];
  const float* clsb  = (const float*)d_in[20];
  const float* regW  = (const float*)d_in[21];
  const float* regb  = (const float*)d_in[22];
  float* out = (float*)d_out;

  uintptr_t base = (uintptr_t)d_ws;
  auto carve = [&](size_t n)->void*{
    void* p = (void*)base; base += (n + 255) & ~(size_t)255; return p;
  };
  u16* Wx0b  = (u16*)carve(2048*32*2);
  u16* We0hh = (u16*)carve(2048*512*2);
  u16* We1ih = (u16*)carve(2048*512*2);
  u16* We1hh = (u16*)carve(2048*512*2);
  u16* Wd0ih = (u16*)carve(2048*512*2);
  u16* Wd0hh = (u16*)carve(2048*512*2);
  u16* Wd1ih = (u16*)carve(2048*512*2);
  u16* Wd1hh = (u16*)carve(2048*512*2);
  float* Bs  = (float*)carve(4*2048*4);
  u16* Xb    = (u16*)carve(256*128*32*2);
  u16* h0b   = (u16*)carve((size_t)4*HB*2);   // depth-4 ring, layer0
  u16* h1b   = (u16*)carve((size_t)4*HB*2);   // depth-4 ring, layer1
  unsigned* F = (unsigned*)carve(256*4);

  // zero h-rings + flags (contiguous 256-aligned carves)
  (void)hipMemsetAsync(h0b, 0, (size_t)4*HB*2 + (size_t)4*HB*2 + 1024, stream);

  reorder_w_k<<<4096,256,0,stream>>>(eWhh0, We0hh);
  reorder_w_k<<<4096,256,0,stream>>>(eWih1, We1ih);
  reorder_w_k<<<4096,256,0,stream>>>(eWhh1, We1hh);
  reorder_w_k<<<4096,256,0,stream>>>(dWih0, Wd0ih);
  reorder_w_k<<<4096,256,0,stream>>>(dWhh0, Wd0hh);
  reorder_w_k<<<4096,256,0,stream>>>(dWih1, Wd1ih);
  reorder_w_k<<<4096,256,0,stream>>>(dWhh1, Wd1hh);
  prep_wx0_k<<<256,256,0,stream>>>(eWih0, Wx0b);
  prep_bias_k<<<8,256,0,stream>>>(ebih0, ebhh0, Bs);
  prep_bias_k<<<8,256,0,stream>>>(ebih1, ebhh1, Bs + 2048);
  prep_bias_k<<<8,256,0,stream>>>(dbih0, dbhh0, Bs + 4096);
  prep_bias_k<<<8,256,0,stream>>>(dbih1, dbhh1, Bs + 6144);
  prep_x_k<<<4096,256,0,stream>>>(x, Xb);
  init_out_k<<<39,256,0,stream>>>(out, fcb, clsb, regb);

  PK p;
  p.Xb = Xb; p.Wx0 = Wx0b; p.W0hh = We0hh; p.W1ih = We1ih; p.W1hh = We1hh;
  p.Wd0ih = Wd0ih; p.Wd0hh = Wd0hh; p.Wd1ih = Wd1ih; p.Wd1hh = Wd1hh;
  p.Bs = Bs; p.h0b = h0b; p.h1b = h1b; p.F = F;
  p.fcW = fcW; p.clsW = clsW; p.regW = regW; p.out = out;

  const int dynLds = 2*64*520*2;   // 133,120 B (two 64x520 u16 weight slices)
  (void)hipFuncSetAttribute((const void*)persist_k,
                            hipFuncAttributeMaxDynamicSharedMemorySize, dynLds);

  // 256 wgs x 128 threads, 1 wg/CU (LDS-forced) -> fully co-resident.
  void* args[] = { &p };
  hipError_t e = hipLaunchCooperativeKernel((const void*)persist_k, dim3(256), dim3(128),
                                            args, dynLds, stream);
  if (e != hipSuccess){
    persist_k<<<dim3(256), dim3(128), dynLds, stream>>>(p);
  }
  (void)in_sizes; (void)n_in; (void)out_size; (void)ws_size;
}

// Round 17
// 2185.588 us; speedup vs baseline: 1.2775x; 1.1380x over previous
//
#include <hip/hip_runtime.h>
#include <hip/hip_bf16.h>

typedef __attribute__((ext_vector_type(8))) short short8;
typedef __attribute__((ext_vector_type(4))) float floatx4;
typedef unsigned short u16;
typedef unsigned long long u64;

#define SCOPE_AGENT __HIP_MEMORY_SCOPE_AGENT

// B=128, T=256, D=6, H=512, 4H=2048, NC=4, PS=12

__device__ __forceinline__ u16 f2b(float f){
  union { float fl; unsigned u; } v; v.fl = f;
  unsigned r = v.u + 0x7fffu + ((v.u >> 16) & 1u);   // RNE bf16
  return (u16)(r >> 16);
}
__device__ __forceinline__ float b2f(u16 b){
  union { unsigned u; float f; } v; v.u = ((unsigned)b) << 16; return v.f;
}

// ---- device-coherent (agent) primitives ----
// agent-scope load = `sc1` on gfx950; 16B wide (coherence, not atomicity).
// ISSUE-ONLY: caller must s_waitcnt vmcnt(0) before consuming.
__device__ __forceinline__ short8 ldc8(const u16* p){
  short8 r;
  asm volatile("global_load_dwordx4 %0, %1, off sc1" : "=&v"(r) : "v"(p));
  return r;
}
__device__ __forceinline__ void stc64(u64* p, u64 v){
  __hip_atomic_store(p, v, __ATOMIC_RELAXED, SCOPE_AGENT);
}

// poll deadline (~0.5 s @ 100 MHz wall clock)
__device__ __forceinline__ bool expired(long long t0){
  return (wall_clock64() - t0) > 50000000LL;
}

// ---------------- prep kernels ----------------

__global__ void reorder_w_k(const float* __restrict__ W, u16* __restrict__ out){
  int idx = blockIdx.x*256 + threadIdx.x;       // 2048*512
  int r = idx >> 9, k = idx & 511;
  int rp = ((r & 511) << 2) | (r >> 9);
  out[rp*512 + k] = f2b(W[idx]);
}
__global__ void prep_wx0_k(const float* __restrict__ W, u16* __restrict__ out){
  int idx = blockIdx.x*256 + threadIdx.x;       // 2048*32
  int r = idx >> 5, k = idx & 31;
  int rp = ((r & 511) << 2) | (r >> 9);
  out[rp*32 + k] = (k < 6) ? f2b(W[r*6 + k]) : (u16)0;
}
__global__ void prep_bias_k(const float* __restrict__ bih, const float* __restrict__ bhh,
                            float* __restrict__ out){
  int r = blockIdx.x*256 + threadIdx.x;         // 2048
  int rp = ((r & 511) << 2) | (r >> 9);
  out[rp] = bih[r] + bhh[r];
}
__global__ void prep_x_k(const float* __restrict__ x, u16* __restrict__ out){
  int idx = blockIdx.x*256 + threadIdx.x;       // 256*128*32
  int t = idx >> 12; int rem = idx & 4095; int b = rem >> 5; int k = rem & 31;
  out[idx] = (k < 6) ? f2b(x[(b*256 + t)*6 + k]) : (u16)0;
}
// pre-fill output with biases; worker wgs atomicAdd head partials on top.
__global__ void init_out_k(float* __restrict__ out, const float* __restrict__ fcb,
                           const float* __restrict__ clsb, const float* __restrict__ regb){
  int i = blockIdx.x*256 + threadIdx.x;         // 9856 total
  if (i < 9216)       out[i] = fcb[i % 6];                 // forecast [128][12][6]
  else if (i < 9728)  out[i] = clsb[(i - 9216) & 3];       // cls [128][4]
  else if (i < 9856)  out[i] = regb[0];                    // reg [128]
}

// ---------------- persistent LSTM kernel ----------------

struct PK {
  const u16 *Xb, *Wx0, *W0hh, *W1ih, *W1hh, *Wd0ih, *Wd0hh, *Wd1ih, *Wd1hh;
  const float *Bs;              // 4x2048 gate-interleaved biases
  u16 *h0b, *h1b;               // bf16 depth-4 h rings [4][128][512], slot = tau&3
  unsigned *F;                  // [0..127]=l0 pools (bg*32+nt), [128..255]=l1
  const float *fcW, *clsW, *regW;
  float *out;
};

#define HB 65536   // u16 elements per ring slot (128 x 512)

// flag poll — wave 0 only (callers barrier afterwards). R8-proven sleep form.
// lanes 0..31: l0(bg) flags vs thr0 ; lanes 32..63: l1(bg) flags vs thr1.
__device__ __forceinline__ void pollF(const unsigned* F, int bg, int thr0, int thr1,
                                      long long t0){
  const int lane = threadIdx.x & 63;
  const unsigned* ap = (lane < 32) ? (F + bg*32 + lane)
                                   : (F + 128 + bg*32 + (lane - 32));
  const int thr = (lane < 32) ? thr0 : thr1;
  for(;;){
    int v = (int)__hip_atomic_load(ap, __ATOMIC_RELAXED, SCOPE_AGENT);
    if (__all(v >= thr)) return;
    if (expired(t0)) return;
    if (__any((thr - v) > 2)) __builtin_amdgcn_s_sleep(16);
    else                      __builtin_amdgcn_s_sleep(1);
  }
}

// One LSTM step tile for wg (role, bg, nt): 32 batches x 64 gates, 4 waves.
// Wave = (rowgrp wv 0..1, K-half kh 0..1). Each wave loads+MFMAs only its
// K-half (2x the in-flight coherent requests per CU vs 2-wave form); kh=1
// partial accumulators are combined into kh=0 via LDS (C/D lane layout is
// K-independent, so the add is lane-aligned). Epilogue/creg/h-store live in
// kh=0 waves (R16-proven paths). hout[] exports h for inline head partials.
template<int NK1, bool COH1>
__device__ __forceinline__ void lstm_step(
    const u16* __restrict__ A1, int a1rowlen, const u16* __restrict__ ldsW1, int st1,
    const u16* __restrict__ A2, const u16* __restrict__ ldsW2,
    const float* __restrict__ biasp, u16* __restrict__ hdst,
    float* creg, float (*g)[69], float* accX, float* hout,
    int bg, int nt, int wv, int kh, int lane)
{
  const int lrow = lane & 15, kq = lane >> 4;
  const int arow = bg*32 + wv*16 + lrow;
  constexpr int NA1 = (NK1 == 1) ? 1 : NK1/2;   // a1 chunks per wave
  const int k1base = (NK1 == 1) ? 0 : kh*NA1;
  const bool hasA1 = (NK1 > 1) || (kh == 0);    // X (single chunk) -> kh0 only
  short8 a1[NA1], a2[8];
  {
    const u16* p1 = A1 + arow*a1rowlen + kq*8;
    if (hasA1){
      #pragma unroll
      for (int k = 0; k < NA1; ++k)
        a1[k] = COH1 ? ldc8(p1 + (k1base+k)*32) : *(const short8*)(p1 + (k1base+k)*32);
    }
    const u16* p2 = A2 + arow*512 + kq*8;
    #pragma unroll
    for (int k = 0; k < 8; ++k) a2[k] = ldc8(p2 + (kh*8+k)*32);
  }
  asm volatile("s_waitcnt vmcnt(0)" ::: "memory");   // drain issue-only sc1 loads
  __builtin_amdgcn_sched_barrier(0);                  // rule #18: keep MFMAs below
  floatx4 acc[4];
  #pragma unroll
  for (int nn = 0; nn < 4; ++nn) acc[nn] = (floatx4){0.f,0.f,0.f,0.f};
  if (hasA1){
    #pragma unroll
    for (int nn = 0; nn < 4; ++nn){
      const u16* wb = ldsW1 + (nn*16 + lrow)*st1 + kq*8;
      #pragma unroll
      for (int k = 0; k < NA1; ++k)
        acc[nn] = __builtin_amdgcn_mfma_f32_16x16x32_bf16(a1[k], *(const short8*)(wb + (k1base+k)*32), acc[nn], 0,0,0);
    }
  }
  #pragma unroll
  for (int nn = 0; nn < 4; ++nn){
    const u16* wb = ldsW2 + (nn*16 + lrow)*520 + kq*8;
    #pragma unroll
    for (int k = 0; k < 8; ++k)
      acc[nn] = __builtin_amdgcn_mfma_f32_16x16x32_bf16(a2[k], *(const short8*)(wb + (kh*8+k)*32), acc[nn], 0,0,0);
  }
  // combine K-halves: kh1 writes partials to LDS, kh0 adds after barrier
  if (kh == 1){
    float* ax = accX + (wv*64 + lane)*16;
    #pragma unroll
    for (int nn = 0; nn < 4; ++nn)
      #pragma unroll
      for (int r = 0; r < 4; ++r) ax[nn*4 + r] = acc[nn][r];
  }
  __syncthreads();
  if (kh == 1) return;    // kh1 waves rejoin at caller's setflag barrier
  {
    const float* ax = accX + (wv*64 + lane)*16;
    #pragma unroll
    for (int nn = 0; nn < 4; ++nn)
      #pragma unroll
      for (int r = 0; r < 4; ++r) acc[nn][r] += ax[nn*4 + r];
  }
  // C/D layout: row(m) = kq*4 + r, col(n) = lane&15 -> g rows wv*16..+15 only
  #pragma unroll
  for (int nn = 0; nn < 4; ++nn){
    float bn = biasp[nn*16 + lrow];
    #pragma unroll
    for (int r = 0; r < 4; ++r)
      g[wv*16 + kq*4 + r][nn*16 + lrow] = acc[nn][r] + bn;
  }
  __builtin_amdgcn_wave_barrier();   // intra-wave LDS transpose
  const int bl = lane >> 2, jq = lane & 3;
  const float* gr = g[wv*16 + bl];
  union { u16 h[4]; u64 q; } pk;
  #pragma unroll
  for (int jj = 0; jj < 4; ++jj){
    int cb = (jq*4 + jj)*4;
    float gi = gr[cb+0], gf = gr[cb+1], gg = gr[cb+2], go = gr[cb+3];
    float iv = 1.f/(1.f + expf(-gi));
    float fv = 1.f/(1.f + expf(-gf));
    float ov = 1.f/(1.f + expf(-go));
    float cn = fv*creg[jj] + iv*tanhf(gg);
    creg[jj] = cn;
    pk.h[jj] = f2b(ov * tanhf(cn));
    hout[jj] = b2f(pk.h[jj]);
  }
  stc64((u64*)(hdst + (bg*32 + wv*16 + bl)*512 + nt*16 + jq*4), pk.q);
}

// Flag protocol — R16-identical, per-(bg) chain (8 independent chains):
//  enc l0 t: f0>=t, f1>=t-3 | enc l1 u: f0>=u+1, f1>=u
//  dec l0 s: f0>=256+s, f1>=256+s | dec l1 s: f0>=257+s, f1>=256+s
// Heads inline in l1 wgs (atomicAdd partials). Ring slot h(tau) = tau&3.

__global__ __launch_bounds__(256, 1) __attribute__((amdgpu_waves_per_eu(1, 1)))
void persist_k(PK p){
  const int w = blockIdx.x, tid = threadIdx.x;
  const int wv2 = tid >> 6, lane = tid & 63;
  const int wv = wv2 & 1, kh = wv2 >> 1;     // (rowgrp, K-half)
  const long long t0 = wall_clock64();
  __shared__ float g[32][69];
  __shared__ float accX[2*64*16];            // kh1 partial accumulators (8KB)
  extern __shared__ u16 dynW[];
  unsigned* F = p.F;

  const int role = w >> 7;              // 0 = layer0, 1 = layer1
  const int bg   = (w >> 5) & 3;        // batch group (32 batches)
  const int nt   = w & 31;              // gate slice (64 gates)
  const int fidx = role*128 + bg*32 + nt;
  u16* WA = dynW;
  u16* WB = dynW + 64*520;
  float creg[4] = {0.f,0.f,0.f,0.f};
  float hout[4];

  auto setflag = [&](unsigned val){
    __syncthreads();   // release: drains vmcnt (h stores) on every wave
    if (tid == 0) __hip_atomic_store(F + fidx, val, __ATOMIC_RELAXED, SCOPE_AGENT);
  };

  if (role == 0){
    { // preload: Wx0 slice (stride 40) + W0hh slice (stride 520)
      const unsigned* sA = (const unsigned*)(p.Wx0 + nt*64*32);
      unsigned* dA = (unsigned*)WA;
      for (int i = tid; i < 64*16; i += 256){ int r = i>>4, c = i&15; dA[r*20+c] = sA[r*16+c]; }
      const unsigned* sB = (const unsigned*)(p.W0hh + (size_t)nt*64*512);
      unsigned* dB = (unsigned*)WB;
      for (int i = tid; i < 64*256; i += 256){ int r = i>>8, c = i&255; dB[r*260+c] = sB[r*256+c]; }
    }
    const float* biasp = p.Bs + nt*64;
    __syncthreads();
    for (int t = 0; t < 256; ++t){
      if (wv2 == 0) pollF(F, bg, t, t-3, t0);
      __syncthreads();
      lstm_step<1,false>(p.Xb + t*4096, 32, WA, 40,
                         p.h0b + ((t+3)&3)*HB, WB,
                         biasp, p.h0b + (t&3)*HB, creg, g, accX, hout, bg, nt, wv, kh, lane);
      setflag(t+1);
    }
    { // reload decoder l0 weights (cell state stays in regs)
      const unsigned* sA = (const unsigned*)(p.Wd0ih + (size_t)nt*64*512);
      const unsigned* sB = (const unsigned*)(p.Wd0hh + (size_t)nt*64*512);
      unsigned* dA = (unsigned*)WA; unsigned* dB = (unsigned*)WB;
      for (int i = tid; i < 64*256; i += 256){
        int r = i>>8, c = i&255;
        dA[r*260+c] = sA[r*256+c]; dB[r*260+c] = sB[r*256+c];
      }
    }
    biasp = p.Bs + 4096 + nt*64;
    __syncthreads();
    for (int s = 0; s < 12; ++s){
      if (wv2 == 0) pollF(F, bg, 256+s, 256+s, t0);
      __syncthreads();
      lstm_step<16,true>(p.h1b + ((s+3)&3)*HB, 512, WA, 520,
                         p.h0b + ((s+3)&3)*HB, WB,
                         biasp, p.h0b + (s&3)*HB, creg, g, accX, hout, bg, nt, wv, kh, lane);
      setflag(257+s);
    }
  } else {
    { // preload: W1ih + W1hh slices
      const unsigned* sA = (const unsigned*)(p.W1ih + (size_t)nt*64*512);
      const unsigned* sB = (const unsigned*)(p.W1hh + (size_t)nt*64*512);
      unsigned* dA = (unsigned*)WA; unsigned* dB = (unsigned*)WB;
      for (int i = tid; i < 64*256; i += 256){
        int r = i>>8, c = i&255;
        dA[r*260+c] = sA[r*256+c]; dB[r*260+c] = sB[r*256+c];
      }
    }
    const float* biasp = p.Bs + 2048 + nt*64;
    __syncthreads();
    const int batch = bg*32 + wv*16 + (lane >> 2);
    const int jq = lane & 3;
    for (int u = 0; u < 256; ++u){
      if (wv2 == 0) pollF(F, bg, u+1, u, t0);
      __syncthreads();
      lstm_step<16,true>(p.h0b + (u&3)*HB, 512, WA, 520,
                         p.h1b + ((u+3)&3)*HB, WB,
                         biasp, p.h1b + (u&3)*HB, creg, g, accX, hout, bg, nt, wv, kh, lane);
      if (u == 255 && kh == 0){
        // cls + reg partials from h1(255) block held in hout (kh0 waves only)
        float a[5] = {0.f,0.f,0.f,0.f,0.f};
        #pragma unroll
        for (int jj = 0; jj < 4; ++jj){
          int col = nt*16 + jq*4 + jj;
          float hv = hout[jj];
          a[0] += hv * p.clsW[col];
          a[1] += hv * p.clsW[512 + col];
          a[2] += hv * p.clsW[1024 + col];
          a[3] += hv * p.clsW[1536 + col];
          a[4] += hv * p.regW[col];
        }
        #pragma unroll
        for (int c = 0; c < 4; ++c) atomicAdd(&p.out[9216 + batch*4 + c], a[c]);
        atomicAdd(&p.out[9728 + batch], a[4]);
      }
      setflag(u+1);
    }
    { // reload decoder l1 weights
      const unsigned* sA = (const unsigned*)(p.Wd1ih + (size_t)nt*64*512);
      const unsigned* sB = (const unsigned*)(p.Wd1hh + (size_t)nt*64*512);
      unsigned* dA = (unsigned*)WA; unsigned* dB = (unsigned*)WB;
      for (int i = tid; i < 64*256; i += 256){
        int r = i>>8, c = i&255;
        dA[r*260+c] = sA[r*256+c]; dB[r*260+c] = sB[r*256+c];
      }
    }
    biasp = p.Bs + 6144 + nt*64;
    __syncthreads();
    for (int s = 0; s < 12; ++s){
      if (wv2 == 0) pollF(F, bg, 257+s, 256+s, t0);
      __syncthreads();
      lstm_step<16,true>(p.h0b + (s&3)*HB, 512, WA, 520,
                         p.h1b + ((s+3)&3)*HB, WB,
                         biasp, p.h1b + (s&3)*HB, creg, g, accX, hout, bg, nt, wv, kh, lane);
      if (kh == 0){
        // forecast partials: out[batch][s][d] += sum_cols h1*fcW (kh0 waves)
        #pragma unroll
        for (int d = 0; d < 6; ++d){
          float ad = 0.f;
          #pragma unroll
          for (int jj = 0; jj < 4; ++jj)
            ad += hout[jj] * p.fcW[d*512 + nt*16 + jq*4 + jj];
          atomicAdd(&p.out[batch*72 + s*6 + d], ad);
        }
      }
      setflag(257+s);
    }
  }
}

// ---------------- launcher ----------------

extern "C" void kernel_launch(void* const* d_in, const int* in_sizes, int n_in,
                              void* d_out, int out_size, void* d_ws, size_t ws_size,
                              hipStream_t stream){
  const float* x     = (const float*)d_in[0];
  const float* eWih0 = (const float*)d_in[1];
  const float* eWhh0 = (const float*)d_in[2];
  const float* ebih0 = (const float*)d_in[3];
  const float* ebhh0 = (const float*)d_in[4];
  const float* eWih1 = (const float*)d_in[5];
  const float* eWhh1 = (const float*)d_in[6];
  const float* ebih1 = (const float*)d_in[7];
  const float* ebhh1 = (const float*)d_in[8];
  const float* dWih0 = (const float*)d_in[9];
  const float* dWhh0 = (const float*)d_in[10];
  const float* dbih0 = (const float*)d_in[11];
  const float* dbhh0 = (const float*)d_in[12];
  const float* dWih1 = (const float*)d_in[13];
  const float* dWhh1 = (const float*)d_in[14];
  const float* dbih1 = (const float*)d_in[15];
  const float* dbhh1 = (const float*)d_in[16];
  const float* fcW   = (const float*)d_in[17];
  const float* fcb   = (const float*)d_in[18];
  const float* clsW  = (const float*)d_in[19];
  const float* clsb  = (const float*)d_in[20];
  const float* regW  = (const float*)d_in[21];
  const float* regb  = (const float*)d_in[22];
  float* out = (float*)d_out;

  uintptr_t base = (uintptr_t)d_ws;
  auto carve = [&](size_t n)->void*{
    void* p = (void*)base; base += (n + 255) & ~(size_t)255; return p;
  };
  u16* Wx0b  = (u16*)carve(2048*32*2);
  u16* We0hh = (u16*)carve(2048*512*2);
  u16* We1ih = (u16*)carve(2048*512*2);
  u16* We1hh = (u16*)carve(2048*512*2);
  u16* Wd0ih = (u16*)carve(2048*512*2);
  u16* Wd0hh = (u16*)carve(2048*512*2);
  u16* Wd1ih = (u16*)carve(2048*512*2);
  u16* Wd1hh = (u16*)carve(2048*512*2);
  float* Bs  = (float*)carve(4*2048*4);
  u16* Xb    = (u16*)carve(256*128*32*2);
  u16* h0b   = (u16*)carve((size_t)4*HB*2);   // depth-4 ring, layer0
  u16* h1b   = (u16*)carve((size_t)4*HB*2);   // depth-4 ring, layer1
  unsigned* F = (unsigned*)carve(256*4);

  // zero h-rings + flags (contiguous 256-aligned carves)
  (void)hipMemsetAsync(h0b, 0, (size_t)4*HB*2 + (size_t)4*HB*2 + 1024, stream);

  reorder_w_k<<<4096,256,0,stream>>>(eWhh0, We0hh);
  reorder_w_k<<<4096,256,0,stream>>>(eWih1, We1ih);
  reorder_w_k<<<4096,256,0,stream>>>(eWhh1, We1hh);
  reorder_w_k<<<4096,256,0,stream>>>(dWih0, Wd0ih);
  reorder_w_k<<<4096,256,0,stream>>>(dWhh0, Wd0hh);
  reorder_w_k<<<4096,256,0,stream>>>(dWih1, Wd1ih);
  reorder_w_k<<<4096,256,0,stream>>>(dWhh1, Wd1hh);
  prep_wx0_k<<<256,256,0,stream>>>(eWih0, Wx0b);
  prep_bias_k<<<8,256,0,stream>>>(ebih0, ebhh0, Bs);
  prep_bias_k<<<8,256,0,stream>>>(ebih1, ebhh1, Bs + 2048);
  prep_bias_k<<<8,256,0,stream>>>(dbih0, dbhh0, Bs + 4096);
  prep_bias_k<<<8,256,0,stream>>>(dbih1, dbhh1, Bs + 6144);
  prep_x_k<<<4096,256,0,stream>>>(x, Xb);
  init_out_k<<<39,256,0,stream>>>(out, fcb, clsb, regb);

  PK p;
  p.Xb = Xb; p.Wx0 = Wx0b; p.W0hh = We0hh; p.W1ih = We1ih; p.W1hh = We1hh;
  p.Wd0ih = Wd0ih; p.Wd0hh = Wd0hh; p.Wd1ih = Wd1ih; p.Wd1hh = Wd1hh;
  p.Bs = Bs; p.h0b = h0b; p.h1b = h1b; p.F = F;
  p.fcW = fcW; p.clsW = clsW; p.regW = regW; p.out = out;

  const int dynLds = 2*64*520*2;   // 133,120 B (two 64x520 u16 weight slices)
  (void)hipFuncSetAttribute((const void*)persist_k,
                            hipFuncAttributeMaxDynamicSharedMemorySize, dynLds);

  // 256 wgs x 256 threads, 1 wg/CU (LDS-forced) -> fully co-resident.
  void* args[] = { &p };
  hipError_t e = hipLaunchCooperativeKernel((const void*)persist_k, dim3(256), dim3(256),
                                            args, dynLds, stream);
  if (e != hipSuccess){
    persist_k<<<dim3(256), dim3(256), dynLds, stream>>>(p);
  }
  (void)in_sizes; (void)n_in; (void)out_size; (void)ws_size;
}